// Round 1
// baseline (515.247 us; speedup 1.0000x reference)
//
#include <hip/hip_runtime.h>

// Conv2D 3x3 VALID, NHWC fp32. B=16 H=W=224 C=32 F=32 -> [16,222,222,32]
// im2col view: M=788544, K=288 (kh,kw,c), N=32.
// Round 0: fp32 VALU baseline. One thread per output pixel, all 32 filters
// accumulated in registers. Weights read via wave-uniform indices -> s_load
// (SGPR operand of v_fma_f32). Input patch via aligned float4 loads.

#define KH 3
#define KW 3
#define CIN 32
#define FOUT 32
#define HIN 224
#define WIN 224
#define HO 222
#define WO 222

__global__ __launch_bounds__(256) void conv3x3_fp32(
    const float* __restrict__ x,     // [B,224,224,32]
    const float* __restrict__ w,     // [F, 3,3,32] flat (f-major, then kh,kw,c)
    const float* __restrict__ bias,  // [32]
    float* __restrict__ out,         // [B,222,222,32]
    int total)                        // B*HO*WO
{
    int idx = blockIdx.x * 256 + threadIdx.x;
    if (idx >= total) return;

    int b  = idx / (HO * WO);
    int r  = idx % (HO * WO);
    int ho = r / WO;
    int wo = r % WO;

    float acc[FOUT];
#pragma unroll
    for (int f = 0; f < FOUT; ++f) acc[f] = bias[f];

    const float* xbase = x + ((static_cast<long>(b) * HIN + ho) * WIN + wo) * CIN;

#pragma unroll 1
    for (int kh = 0; kh < KH; ++kh) {
#pragma unroll 1
        for (int kw = 0; kw < KW; ++kw) {
            const float* xp = xbase + (kh * WIN + kw) * CIN;  // 128B-aligned
            float4 xv[CIN / 4];
#pragma unroll
            for (int i = 0; i < CIN / 4; ++i)
                xv[i] = reinterpret_cast<const float4*>(xp)[i];

            const float* wp = w + (kh * KW + kw) * CIN;  // uniform across wave
#pragma unroll
            for (int f = 0; f < FOUT; ++f) {
                const float* wf = wp + f * (KH * KW * CIN);
#pragma unroll
                for (int i = 0; i < CIN / 4; ++i) {
                    acc[f] += xv[i].x * wf[i * 4 + 0];
                    acc[f] += xv[i].y * wf[i * 4 + 1];
                    acc[f] += xv[i].z * wf[i * 4 + 2];
                    acc[f] += xv[i].w * wf[i * 4 + 3];
                }
            }
        }
    }

    float* op = out + static_cast<long>(idx) * FOUT;
#pragma unroll
    for (int i = 0; i < FOUT / 4; ++i) {
        float4 v;
        v.x = acc[i * 4 + 0];
        v.y = acc[i * 4 + 1];
        v.z = acc[i * 4 + 2];
        v.w = acc[i * 4 + 3];
        reinterpret_cast<float4*>(op)[i] = v;
    }
}

extern "C" void kernel_launch(void* const* d_in, const int* in_sizes, int n_in,
                              void* d_out, int out_size, void* d_ws, size_t ws_size,
                              hipStream_t stream) {
    const float* x    = (const float*)d_in[0];
    const float* w    = (const float*)d_in[1];
    const float* bias = (const float*)d_in[2];
    float* out        = (float*)d_out;

    const int total = 16 * HO * WO;  // 788544 output pixels
    const int block = 256;
    const int grid  = (total + block - 1) / block;
    conv3x3_fp32<<<grid, block, 0, stream>>>(x, w, bias, out, total);
}

// Round 2
// 165.703 us; speedup vs baseline: 3.1095x; 3.1095x over previous
//
#include <hip/hip_runtime.h>

// Conv2D 3x3 VALID NHWC, B=16 H=W=224 C=32 F=32 -> [16,222,222,32] fp32.
// im2col GEMM M=788544 K=288 N=32, bf16 MFMA 16x16x32.
// Block = 512 thr (8 waves) -> 8x64 output tile of one image.
// Input patch staged fp32->bf16 in LDS once (kills the 9x HBM re-fetch seen
// in round 0: FETCH was 972 MB vs 103 MB ideal). Weights held in registers
// as MFMA B-fragments (18 x short8 = 72 VGPR).

#define HO 222
#define WO 222
#define HIN 224
#define WIN 224
#define CIN 32
#define FOUT 32

#define TH 8                     // output rows per block
#define TW 64                    // output cols per block
#define IR (TH + 2)              // 10 input rows staged
#define IC (TW + 2)              // 66 input cols staged
#define PIX_STRIDE 80            // bytes/pixel in LDS: 32 bf16 (64B) + 16B pad -> 20-bank stride, <=2-way
#define ROW_STRIDE (IC * PIX_STRIDE)   // 5280 B
#define LDS_BYTES (IR * ROW_STRIDE)    // 52800 B -> 2 blocks/CU

typedef __attribute__((ext_vector_type(8))) short short8;   // 8 bf16 = 4 VGPR
typedef __attribute__((ext_vector_type(4))) short short4v;  // 4 bf16 = 8 B
typedef __attribute__((ext_vector_type(4))) float float4v;

__device__ inline short f2bf(float f) {                     // RNE fp32->bf16
    unsigned u = __builtin_bit_cast(unsigned, f);
    unsigned r = (u + 0x7FFFu + ((u >> 16) & 1u)) >> 16;
    return (short)r;
}

__global__ __launch_bounds__(512, 4) void conv3x3_mfma(
    const float* __restrict__ x,     // [16,224,224,32]
    const float* __restrict__ w,     // [32 filters][288 = (kh,kw,c)]
    const float* __restrict__ bias,  // [32]
    float* __restrict__ out)         // [16,222,222,32]
{
    __shared__ uint4 lds_raw[LDS_BYTES / 16];
    char* lds = reinterpret_cast<char*>(lds_raw);

    const int wot = blockIdx.x;            // 0..3
    const int hot = blockIdx.y;            // 0..27
    const int b   = blockIdx.z;            // 0..15
    const int wo_base = wot * TW;
    const int ho_base = hot * TH;

    const int tid  = threadIdx.x;
    const int lane = tid & 63;
    const int wave = tid >> 6;             // 0..7

    const int fcol = lane & 15;            // filter col (B n-index, D col)
    const int kq   = lane >> 4;            // k-quarter: k = kq*8 + i

    // ---- weights -> register B-fragments (chunk-invariant) ----
    short8 bfr[2][9];
#pragma unroll
    for (int h = 0; h < 2; ++h) {
        const float* wf = w + (h * 16 + fcol) * 288 + kq * 8;
#pragma unroll
        for (int s = 0; s < 9; ++s) {
            const float4* wp = reinterpret_cast<const float4*>(wf + s * 32);
            float4 lo = wp[0];
            float4 hi = wp[1];
            short8 v;
            v[0] = f2bf(lo.x); v[1] = f2bf(lo.y); v[2] = f2bf(lo.z); v[3] = f2bf(lo.w);
            v[4] = f2bf(hi.x); v[5] = f2bf(hi.y); v[6] = f2bf(hi.z); v[7] = f2bf(hi.w);
            bfr[h][s] = v;
        }
    }
    const float bias0 = bias[fcol];
    const float bias1 = bias[fcol + 16];

    // ---- stage input tile fp32 -> bf16 into LDS ----
    // IR*IC pixels * 8 float4 each = 5280 vector loads
    for (int idx = tid; idx < IR * IC * 8; idx += 512) {
        int c4  = idx & 7;
        int p   = idx >> 3;
        int col = p % IC;
        int row = p / IC;
        int ir  = ho_base + row; if (ir > HIN - 1) ir = HIN - 1;   // clamp: garbage only feeds invalid outputs
        int icl = wo_base + col; if (icl > WIN - 1) icl = WIN - 1;
        float4 v = *reinterpret_cast<const float4*>(
            x + ((b * HIN + ir) * WIN + icl) * CIN + c4 * 4);
        short4v s4;
        s4[0] = f2bf(v.x); s4[1] = f2bf(v.y); s4[2] = f2bf(v.z); s4[3] = f2bf(v.w);
        *reinterpret_cast<short4v*>(lds + p * PIX_STRIDE + c4 * 8) = s4;
    }
    __syncthreads();

    // ---- compute: 4 chunks of 16 pixels per wave ----
    const int m = lane & 15;               // A row = pixel within chunk
#pragma unroll 1
    for (int j = 0; j < 4; ++j) {
        const int chunk = wave * 4 + j;
        const int pix = chunk * 16 + m;
        const int hoo = pix >> 6;          // TW = 64 -> free div
        const int woo = pix & 63;
        const char* abase = lds + (hoo * IC + woo) * PIX_STRIDE + kq * 16;

        float4v acc0 = {0.f, 0.f, 0.f, 0.f};
        float4v acc1 = {0.f, 0.f, 0.f, 0.f};
#pragma unroll
        for (int s = 0; s < 9; ++s) {
            const int kh = s / 3, kw = s % 3;
            short8 a = *reinterpret_cast<const short8*>(
                abase + kh * ROW_STRIDE + kw * PIX_STRIDE);
            acc0 = __builtin_amdgcn_mfma_f32_16x16x32_bf16(a, bfr[0][s], acc0, 0, 0, 0);
            acc1 = __builtin_amdgcn_mfma_f32_16x16x32_bf16(a, bfr[1][s], acc1, 0, 0, 0);
        }

        // D layout: col = lane&15 (filter), row = (lane>>4)*4 + r (pixel)
        const int rbase = chunk * 16 + (lane >> 4) * 4;
#pragma unroll
        for (int r = 0; r < 4; ++r) {
            int pm = rbase + r;
            int ho = ho_base + (pm >> 6);
            int wo = wo_base + (pm & 63);
            if (ho < HO && wo < WO) {
                float* o = out + ((b * HO + ho) * WO + wo) * FOUT;
                o[fcol]      = acc0[r] + bias0;
                o[fcol + 16] = acc1[r] + bias1;
            }
        }
    }
}

extern "C" void kernel_launch(void* const* d_in, const int* in_sizes, int n_in,
                              void* d_out, int out_size, void* d_ws, size_t ws_size,
                              hipStream_t stream) {
    const float* x    = (const float*)d_in[0];
    const float* w    = (const float*)d_in[1];
    const float* bias = (const float*)d_in[2];
    float* out        = (float*)d_out;

    dim3 grid(4, 28, 16);   // ceil(222/64), ceil(222/8), B
    dim3 block(512);
    conv3x3_mfma<<<grid, block, 0, stream>>>(x, w, bias, out);
}

// Round 3
// 135.198 us; speedup vs baseline: 3.8110x; 1.2256x over previous
//
#include <hip/hip_runtime.h>

// Conv2D 3x3 VALID NHWC, B=16 H=W=224 C=32 F=32 -> [16,222,222,32] fp32.
// im2col GEMM M=788544 K=288 N=32, bf16 MFMA 16x16x32.
// Round 3: fix memory-latency bound (R2: 2.5 B/cyc/CU, MfmaUtil 3.6%,
// VALUBusy 11% -- all idle). T14 issue-early/write-late staging: all 11
// float4 loads issued back-to-back (176 B/thread in flight), then convert +
// ds_write, then weight loads overlap the barrier. Weights after converts so
// xv[] and bfr[] never coexist (VGPR <= 128 -> 2 blocks/CU).

#define HO 222
#define WO 222
#define HIN 224
#define WIN 224
#define CIN 32
#define FOUT 32

#define TH 8                     // output rows per block
#define TW 64                    // output cols per block
#define IR (TH + 2)              // 10 input rows staged
#define IC (TW + 2)              // 66 input cols staged
#define PIX_STRIDE 80            // bytes/pixel: 64B bf16 + 16B pad (16B-aligned, conflict-benign)
#define ROW_STRIDE (IC * PIX_STRIDE)   // 5280 B
#define LDS_BYTES (IR * ROW_STRIDE)    // 52800 B
#define NLOAD ((IR * IC * 8 + 511) / 512)  // 11 float4 loads per thread

typedef __attribute__((ext_vector_type(8))) short short8;   // 8 bf16 = 4 VGPR
typedef __attribute__((ext_vector_type(4))) short short4v;  // 4 bf16 = 8 B
typedef __attribute__((ext_vector_type(4))) float float4v;

__device__ inline short f2bf(float f) {                     // RNE fp32->bf16
    unsigned u = __builtin_bit_cast(unsigned, f);
    unsigned r = (u + 0x7FFFu + ((u >> 16) & 1u)) >> 16;
    return (short)r;
}

__global__ __launch_bounds__(512, 4) void conv3x3_mfma(
    const float* __restrict__ x,     // [16,224,224,32]
    const float* __restrict__ w,     // [32 filters][288 = (kh,kw,c)]
    const float* __restrict__ bias,  // [32]
    float* __restrict__ out)         // [16,222,222,32]
{
    __shared__ uint4 lds_raw[LDS_BYTES / 16];
    char* lds = reinterpret_cast<char*>(lds_raw);

    const int wot = blockIdx.x;            // 0..3
    const int hot = blockIdx.y;            // 0..27
    const int b   = blockIdx.z;            // 0..15
    const int wo_base = wot * TW;
    const int ho_base = hot * TH;

    const int tid  = threadIdx.x;
    const int lane = tid & 63;
    const int wave = tid >> 6;             // 0..7

    // ---- phase 1: issue ALL staging loads (stay in flight together) ----
    float4 xv[NLOAD];
#pragma unroll
    for (int i = 0; i < NLOAD; ++i) {
        int idx = tid + i * 512;
        idx = idx > IR * IC * 8 - 1 ? IR * IC * 8 - 1 : idx;  // dup tail, same data
        int c4  = idx & 7;
        int p   = idx >> 3;
        int row = p / IC;
        int col = p % IC;
        int ir  = ho_base + row; ir = ir > HIN - 1 ? HIN - 1 : ir;  // clamp: feeds only invalid outputs
        int icl = wo_base + col; icl = icl > WIN - 1 ? WIN - 1 : icl;
        xv[i] = *reinterpret_cast<const float4*>(
            x + ((b * HIN + ir) * WIN + icl) * CIN + c4 * 4);
    }

    // ---- phase 2: convert + LDS write ----
#pragma unroll
    for (int i = 0; i < NLOAD; ++i) {
        int idx = tid + i * 512;
        idx = idx > IR * IC * 8 - 1 ? IR * IC * 8 - 1 : idx;
        int c4 = idx & 7;
        int p  = idx >> 3;
        short4v s4;
        s4[0] = f2bf(xv[i].x); s4[1] = f2bf(xv[i].y);
        s4[2] = f2bf(xv[i].z); s4[3] = f2bf(xv[i].w);
        *reinterpret_cast<short4v*>(lds + p * PIX_STRIDE + c4 * 8) = s4;
    }

    // ---- phase 3: weights -> register B-fragments (L2-hot; overlaps barrier) ----
    const int fcol = lane & 15;            // filter col (B n-index, D col)
    const int kq   = lane >> 4;            // k-quarter: k = kq*8 + i
    short8 bfr[2][9];
#pragma unroll
    for (int h = 0; h < 2; ++h) {
        const float* wf = w + (h * 16 + fcol) * 288 + kq * 8;
#pragma unroll
        for (int s = 0; s < 9; ++s) {
            const float4* wp = reinterpret_cast<const float4*>(wf + s * 32);
            float4 lo = wp[0];
            float4 hi = wp[1];
            short8 v;
            v[0] = f2bf(lo.x); v[1] = f2bf(lo.y); v[2] = f2bf(lo.z); v[3] = f2bf(lo.w);
            v[4] = f2bf(hi.x); v[5] = f2bf(hi.y); v[6] = f2bf(hi.z); v[7] = f2bf(hi.w);
            bfr[h][s] = v;
        }
    }
    const float bias0 = bias[fcol];
    const float bias1 = bias[fcol + 16];

    __syncthreads();

    // ---- phase 4: compute: 4 chunks of 16 pixels per wave ----
    const int m = lane & 15;               // A row = pixel within chunk
#pragma unroll 1
    for (int j = 0; j < 4; ++j) {
        const int chunk = wave * 4 + j;
        const int pix = chunk * 16 + m;
        const int hoo = pix >> 6;          // TW = 64 -> free div
        const int woo = pix & 63;
        const char* abase = lds + (hoo * IC + woo) * PIX_STRIDE + kq * 16;

        float4v acc0 = {0.f, 0.f, 0.f, 0.f};
        float4v acc1 = {0.f, 0.f, 0.f, 0.f};
#pragma unroll
        for (int s = 0; s < 9; ++s) {
            const int kh = s / 3, kw = s % 3;
            short8 a = *reinterpret_cast<const short8*>(
                abase + kh * ROW_STRIDE + kw * PIX_STRIDE);
            acc0 = __builtin_amdgcn_mfma_f32_16x16x32_bf16(a, bfr[0][s], acc0, 0, 0, 0);
            acc1 = __builtin_amdgcn_mfma_f32_16x16x32_bf16(a, bfr[1][s], acc1, 0, 0, 0);
        }

        // D layout: col = lane&15 (filter), row = (lane>>4)*4 + r (pixel)
        const int rbase = chunk * 16 + (lane >> 4) * 4;
#pragma unroll
        for (int r = 0; r < 4; ++r) {
            int pm = rbase + r;
            int ho = ho_base + (pm >> 6);
            int wo = wo_base + (pm & 63);
            if (ho < HO && wo < WO) {
                float* o = out + ((b * HO + ho) * WO + wo) * FOUT;
                o[fcol]      = acc0[r] + bias0;
                o[fcol + 16] = acc1[r] + bias1;
            }
        }
    }
}

extern "C" void kernel_launch(void* const* d_in, const int* in_sizes, int n_in,
                              void* d_out, int out_size, void* d_ws, size_t ws_size,
                              hipStream_t stream) {
    const float* x    = (const float*)d_in[0];
    const float* w    = (const float*)d_in[1];
    const float* bias = (const float*)d_in[2];
    float* out        = (float*)d_out;

    dim3 grid(4, 28, 16);   // ceil(222/64), ceil(222/8), B
    dim3 block(512);
    conv3x3_mfma<<<grid, block, 0, stream>>>(x, w, bias, out);
}

// Round 4
// 118.467 us; speedup vs baseline: 4.3493x; 1.1412x over previous
//
#include <hip/hip_runtime.h>

// Conv2D 3x3 VALID NHWC, B=16 H=W=224 C=32 F=32 -> [16,222,222,32] fp32.
// im2col GEMM M=788544 K=288 N=32, bf16 MFMA 16x16x32.
// Round 4:
//  (a) operand swap: D[filter][pixel] = mfma(W, X) so each lane owns 4
//      consecutive filters of one pixel -> contiguous float4 stores
//      (R3 WRITE_SIZE was 235 MB vs 101 ideal with scattered dword stores).
//  (b) cross-tile double-buffered pipeline: each block walks 7 vertical
//      4x64 tiles; loads(t+1) issue before compute(t), convert+ds_write
//      after -> HBM latency hides under MFMA (R3 was stage/compute
//      serialized: MfmaUtil 4%, VALU 13%, HBM 30%, all idle).

#define HO 222
#define WO 222
#define HIN 224
#define WIN 224
#define CIN 32
#define FOUT 32

#define TH 4                     // output rows per tile
#define TW 64                    // output cols per tile
#define IR (TH + 2)              // 6 input rows staged
#define IC (TW + 2)              // 66 input cols staged
#define PIX_STRIDE 80            // 64B bf16 + 16B pad (keeps b128 16B-aligned)
#define ROW_STRIDE (IC * PIX_STRIDE)     // 5280 B
#define BUF_BYTES (IR * ROW_STRIDE)      // 31680 B per buffer, x2 = 63360
#define NT 7                     // tiles per block (56 row-tiles / 8 groups)
#define STAGE_ITEMS (IR * IC * 8)        // 3168 float4 loads per tile
#define NLOAD 7                  // ceil(3168/512)

typedef __attribute__((ext_vector_type(8))) short short8;   // 8 bf16
typedef __attribute__((ext_vector_type(4))) short short4v;  // 4 bf16 = 8 B
typedef __attribute__((ext_vector_type(4))) float float4v;

__device__ inline short f2bf(float f) {                     // RNE fp32->bf16
    unsigned u = __builtin_bit_cast(unsigned, f);
    unsigned r = (u + 0x7FFFu + ((u >> 16) & 1u)) >> 16;
    return (short)r;
}

__global__ __launch_bounds__(512, 4) void conv3x3_mfma(
    const float* __restrict__ x,     // [16,224,224,32]
    const float* __restrict__ w,     // [32 filters][288 = (kh,kw,c)]
    const float* __restrict__ bias,  // [32]
    float* __restrict__ out)         // [16,222,222,32]
{
    __shared__ uint4 lds_raw[2][BUF_BYTES / 16];

    const int wot = blockIdx.x;            // 0..3
    const int g   = blockIdx.y;            // 0..7  (7 tiles each)
    const int b   = blockIdx.z;            // 0..15
    const int wo_base = wot * TW;

    const int tid  = threadIdx.x;
    const int lane = tid & 63;
    const int wave = tid >> 6;             // 0..7

    const int fcol = lane & 15;            // A row (filter) / B col (pixel)
    const int kq   = lane >> 4;            // k = kq*8 + i

    // ---- weights -> register A-fragments (lane holds filter fcol, k-slice kq) ----
    short8 bfr[2][9];
#pragma unroll
    for (int h = 0; h < 2; ++h) {
        const float* wf = w + (h * 16 + fcol) * 288 + kq * 8;
#pragma unroll
        for (int s = 0; s < 9; ++s) {
            const float4* wp = reinterpret_cast<const float4*>(wf + s * 32);
            float4 lo = wp[0];
            float4 hi = wp[1];
            short8 v;
            v[0] = f2bf(lo.x); v[1] = f2bf(lo.y); v[2] = f2bf(lo.z); v[3] = f2bf(lo.w);
            v[4] = f2bf(hi.x); v[5] = f2bf(hi.y); v[6] = f2bf(hi.z); v[7] = f2bf(hi.w);
            bfr[h][s] = v;
        }
    }
    // bias for the 4 filters this lane stores (acc0: kq*4.., acc1: 16+kq*4..)
    const float4 bias0 = reinterpret_cast<const float4*>(bias)[kq];
    const float4 bias1 = reinterpret_cast<const float4*>(bias)[4 + kq];

    float4 xv[NLOAD];

    // ---------- staging helpers ----------
#define LOADS(T)                                                              \
    {                                                                         \
        const int hot4 = (g * NT + (T)) * TH;                                 \
        _Pragma("unroll")                                                     \
        for (int i = 0; i < NLOAD; ++i) {                                     \
            int idx = tid + i * 512;                                          \
            if (idx >= STAGE_ITEMS) idx = STAGE_ITEMS - 1;                    \
            int c4  = idx & 7;                                                \
            int p   = idx >> 3;                                               \
            int row = p / IC;                                                 \
            int col = p - row * IC;                                           \
            int ir  = hot4 + row;   if (ir  > HIN - 1) ir  = HIN - 1;         \
            int icl = wo_base + col; if (icl > WIN - 1) icl = WIN - 1;        \
            xv[i] = *reinterpret_cast<const float4*>(                         \
                x + ((b * HIN + ir) * WIN + icl) * CIN + c4 * 4);             \
        }                                                                     \
    }

#define CONVERT_WRITE(BUFIDX)                                                 \
    {                                                                         \
        char* wbuf = reinterpret_cast<char*>(lds_raw[(BUFIDX)]);              \
        _Pragma("unroll")                                                     \
        for (int i = 0; i < NLOAD; ++i) {                                     \
            int idx = tid + i * 512;                                          \
            if (idx >= STAGE_ITEMS) idx = STAGE_ITEMS - 1;                    \
            int c4 = idx & 7;                                                 \
            int p  = idx >> 3;                                                \
            short4v s4;                                                       \
            s4[0] = f2bf(xv[i].x); s4[1] = f2bf(xv[i].y);                     \
            s4[2] = f2bf(xv[i].z); s4[3] = f2bf(xv[i].w);                     \
            *reinterpret_cast<short4v*>(wbuf + p * PIX_STRIDE + c4 * 8) = s4; \
        }                                                                     \
    }

    // ---------- prologue: stage tile 0 ----------
    LOADS(0);
    CONVERT_WRITE(0);
    __syncthreads();

    // ---------- pipelined tile loop ----------
#pragma unroll 1
    for (int t = 0; t < NT; ++t) {
        if (t + 1 < NT) LOADS(t + 1);              // issue early (in-flight over compute)

        const char* buf = reinterpret_cast<const char*>(lds_raw[t & 1]);
        const int hot4 = (g * NT + t) * TH;

#pragma unroll
        for (int j = 0; j < 2; ++j) {
            const int chunk = wave * 2 + j;        // 16 chunks of 16 pixels
            const int pix = chunk * 16 + fcol;     // B col = pixel
            const int hoo = pix >> 6;              // TW=64
            const int woo = pix & 63;
            const char* abase = buf + (hoo * IC + woo) * PIX_STRIDE + kq * 16;

            float4v acc0 = {0.f, 0.f, 0.f, 0.f};
            float4v acc1 = {0.f, 0.f, 0.f, 0.f};
#pragma unroll
            for (int s = 0; s < 9; ++s) {
                const int kh = s / 3, kw = s % 3;
                short8 a = *reinterpret_cast<const short8*>(
                    abase + kh * ROW_STRIDE + kw * PIX_STRIDE);
                acc0 = __builtin_amdgcn_mfma_f32_16x16x32_bf16(bfr[0][s], a, acc0, 0, 0, 0);
                acc1 = __builtin_amdgcn_mfma_f32_16x16x32_bf16(bfr[1][s], a, acc1, 0, 0, 0);
            }

            // D[filter][pixel]: col(lane&15)=pixel, row=(kq*4+r)=filter
            const int ho = hot4 + hoo;
            const int wo = wo_base + woo;
            if (ho < HO && wo < WO) {
                float* o = out + ((b * HO + ho) * WO + wo) * FOUT;
                float4 v0 = {acc0[0] + bias0.x, acc0[1] + bias0.y,
                             acc0[2] + bias0.z, acc0[3] + bias0.w};
                float4 v1 = {acc1[0] + bias1.x, acc1[1] + bias1.y,
                             acc1[2] + bias1.z, acc1[3] + bias1.w};
                reinterpret_cast<float4*>(o)[kq]     = v0;   // filters kq*4..+3
                reinterpret_cast<float4*>(o)[4 + kq] = v1;   // filters 16+kq*4..+3
            }
        }

        if (t + 1 < NT) CONVERT_WRITE((t + 1) & 1);  // write late (after compute)
        __syncthreads();
    }
#undef LOADS
#undef CONVERT_WRITE
}

extern "C" void kernel_launch(void* const* d_in, const int* in_sizes, int n_in,
                              void* d_out, int out_size, void* d_ws, size_t ws_size,
                              hipStream_t stream) {
    const float* x    = (const float*)d_in[0];
    const float* w    = (const float*)d_in[1];
    const float* bias = (const float*)d_in[2];
    float* out        = (float*)d_out;

    dim3 grid(4, 8, 16);    // wot, hot-group (7 tiles each), batch -> 512 blocks
    dim3 block(512);
    conv3x3_mfma<<<grid, block, 0, stream>>>(x, w, bias, out);
}

// Round 5
// 69.238 us; speedup vs baseline: 7.4417x; 1.7110x over previous
//
#include <hip/hip_runtime.h>

// Conv2D 3x3 VALID NHWC, B=16 H=W=224 C=32 F=32 -> [16,222,222,32] fp32.
// im2col GEMM M=788544 K=288 N=32, bf16 MFMA 16x16x32 (swapped: D[filt][pix]).
// Round 5: R4 was still latency-bound (MfmaUtil 4.8%, VALU 8.2%, HBM 38%) and
// VGPR_Count=64 proved the register-staged pipeline never materialized
// (spill traffic = the +100MB WRITE / +70MB FETCH anomalies).
//  -> global_load_lds width=16 direct fp32 staging (zero staging VGPRs),
//     bf16 convert on fragment read (VALU has headroom).
//  -> counted s_waitcnt vmcnt(6) + raw s_barrier (T4): prefetch loads stay
//     in flight across the barrier; HBM queue never drains.
//  -> G21 both-sides XOR swizzle (source granule ^ read addr) since
//     gload_lds needs a linear LDS dest; kills the 16-way ds_read conflict.

#define HO 222
#define WO 222
#define HIN 224
#define WIN 224
#define CIN 32
#define FOUT 32

#define TH 4                      // output rows per tile
#define TW 64                     // output cols per tile
#define IR (TH + 2)               // 6 staged rows
#define IC (TW + 2)               // 66 staged cols
#define NT 7                      // tiles per block
#define PIXB 128                  // bytes per staged fp32 pixel (32 ch)
#define STAGE_GR (IR * IC * 8)    // 3168 16B-granules per tile
#define BUF_GR (STAGE_GR + 64)    // +64 slack: tail wave's fixed lane pattern overflows
#define NSTG 7                    // ceil(3168/512) gload_lds per thread

typedef __attribute__((ext_vector_type(8))) short short8;
typedef __attribute__((ext_vector_type(4))) float float4v;

__device__ inline short f2bf(float f) {                  // RNE fp32->bf16
    unsigned u = __builtin_bit_cast(unsigned, f);
    unsigned r = (u + 0x7FFFu + ((u >> 16) & 1u)) >> 16;
    return (short)r;
}

__global__ __launch_bounds__(512, 2) void conv3x3_mfma(
    const float* __restrict__ x,     // [16,224,224,32]
    const float* __restrict__ w,     // [32][288 = (kh,kw,c)]
    const float* __restrict__ bias,  // [32]
    float* __restrict__ out)         // [16,222,222,32]
{
    __shared__ uint4 lds_raw[2][BUF_GR];   // 2 x 51712 B = 103424 B -> 1 block/CU

    const int wot = blockIdx.x;            // 0..3
    const int g   = blockIdx.y;            // 0..7
    const int b   = blockIdx.z;            // 0..15
    const int wo_base = wot * TW;

    const int tid  = threadIdx.x;
    const int lane = tid & 63;
    const int wave = tid >> 6;             // 0..7

    const int fcol = lane & 15;            // A row (filter) / D col (pixel)
    const int kq   = lane >> 4;            // k-slice: k = kq*8 + i

    // ---- weights -> register A-fragments (lane: filter fcol, k-slice kq) ----
    short8 bfr[2][9];
#pragma unroll
    for (int h = 0; h < 2; ++h) {
        const float* wf = w + (h * 16 + fcol) * 288 + kq * 8;
#pragma unroll
        for (int s = 0; s < 9; ++s) {
            float4 lo = reinterpret_cast<const float4*>(wf + s * 32)[0];
            float4 hi = reinterpret_cast<const float4*>(wf + s * 32)[1];
            short8 v;
            v[0] = f2bf(lo.x); v[1] = f2bf(lo.y); v[2] = f2bf(lo.z); v[3] = f2bf(lo.w);
            v[4] = f2bf(hi.x); v[5] = f2bf(hi.y); v[6] = f2bf(hi.z); v[7] = f2bf(hi.w);
            bfr[h][s] = v;
        }
    }
    const float4 bias0 = reinterpret_cast<const float4*>(bias)[kq];      // filters kq*4..+3
    const float4 bias1 = reinterpret_cast<const float4*>(bias)[4 + kq];  // filters 16+kq*4..+3

    // ---- async staging: global fp32 -> LDS, source pre-swizzled (G21) ----
    // LDS[gid] = G[swz(gid)], swz = XOR granule-within-pixel with (pixel&7).
    auto STAGE = [&](int bufidx, int t) {
        char* buf = reinterpret_cast<char*>(lds_raw[bufidx]);
        const int row0 = (g * NT + t) * TH;
#pragma unroll
        for (int i = 0; i < NSTG; ++i) {
            if (i * 512 + (tid & ~63) < STAGE_GR) {          // whole-wave predicate
                int gid = tid + i * 512;                      // linear LDS granule
                int gg  = gid < STAGE_GR ? gid : STAGE_GR - 1;  // tail lanes -> safe src, dest lands in slack
                int plin = gg >> 3;                           // staged pixel index
                int sub  = (gg & 7) ^ (plin & 7);             // swizzled source granule
                int row  = plin / IC;
                int col  = plin - row * IC;
                int ir  = row0 + row;    if (ir  > HIN - 1) ir  = HIN - 1;  // clamp feeds only invalid outputs
                int icl = wo_base + col; if (icl > WIN - 1) icl = WIN - 1;
                const float* src = x + ((b * HIN + ir) * WIN + icl) * CIN + sub * 4;
                __builtin_amdgcn_global_load_lds(
                    (const __attribute__((address_space(1))) void*)src,
                    (__attribute__((address_space(3))) void*)(buf + gid * 16),
                    16, 0, 0);
            }
        }
    };

    // ---------- prologue ----------
    STAGE(0, 0);

    // ---------- pipelined tile loop (2-phase, counted vmcnt) ----------
#pragma unroll 1
    for (int t = 0; t < NT; ++t) {
        if (t + 1 < NT) {
            STAGE((t + 1) & 1, t + 1);                       // prefetch next tile
            asm volatile("s_waitcnt vmcnt(6)" ::: "memory"); // tile-t loads done; t+1 stays in flight
        } else {
            asm volatile("s_waitcnt vmcnt(0)" ::: "memory");
        }
        __builtin_amdgcn_s_barrier();
        __builtin_amdgcn_sched_barrier(0);

        const char* buf = reinterpret_cast<const char*>(lds_raw[t & 1]);
        const int row0 = (g * NT + t) * TH;

#pragma unroll
        for (int j = 0; j < 2; ++j) {
            const int chunk = wave * 2 + j;                  // 16 chunks of 16 pixels
            const int pix = chunk * 16 + fcol;
            const int hoo = pix >> 6;
            const int woo = pix & 63;

            float4v acc0 = {0.f, 0.f, 0.f, 0.f};
            float4v acc1 = {0.f, 0.f, 0.f, 0.f};
#pragma unroll
            for (int s = 0; s < 9; ++s) {
                const int kh = s / 3, kw = s % 3;
                const int plin = (hoo + kh) * IC + (woo + kw);
                const int key = (plin & 7) << 4;
                const char* p0 = buf + plin * PIXB + ((kq * 32) ^ key);
                const char* p1 = buf + plin * PIXB + ((kq * 32 + 16) ^ key);
                float4 fa = *reinterpret_cast<const float4*>(p0);  // ch kq*8..+3
                float4 fb = *reinterpret_cast<const float4*>(p1);  // ch kq*8+4..+7
                short8 a;
                a[0] = f2bf(fa.x); a[1] = f2bf(fa.y); a[2] = f2bf(fa.z); a[3] = f2bf(fa.w);
                a[4] = f2bf(fb.x); a[5] = f2bf(fb.y); a[6] = f2bf(fb.z); a[7] = f2bf(fb.w);
                acc0 = __builtin_amdgcn_mfma_f32_16x16x32_bf16(bfr[0][s], a, acc0, 0, 0, 0);
                acc1 = __builtin_amdgcn_mfma_f32_16x16x32_bf16(bfr[1][s], a, acc1, 0, 0, 0);
            }

            // D[filter][pixel]: col(lane&15)=pixel, row=kq*4+r=filter
            const int ho = row0 + hoo;
            const int wo = wo_base + woo;
            if (ho < HO && wo < WO) {
                float* o = out + ((b * HO + ho) * WO + wo) * FOUT;
                float4 v0 = {acc0[0] + bias0.x, acc0[1] + bias0.y,
                             acc0[2] + bias0.z, acc0[3] + bias0.w};
                float4 v1 = {acc1[0] + bias1.x, acc1[1] + bias1.y,
                             acc1[2] + bias1.z, acc1[3] + bias1.w};
                reinterpret_cast<float4*>(o)[kq]     = v0;
                reinterpret_cast<float4*>(o)[4 + kq] = v1;
            }
        }

        __builtin_amdgcn_sched_barrier(0);
        __builtin_amdgcn_s_barrier();
        __builtin_amdgcn_sched_barrier(0);
    }
}

extern "C" void kernel_launch(void* const* d_in, const int* in_sizes, int n_in,
                              void* d_out, int out_size, void* d_ws, size_t ws_size,
                              hipStream_t stream) {
    const float* x    = (const float*)d_in[0];
    const float* w    = (const float*)d_in[1];
    const float* bias = (const float*)d_in[2];
    float* out        = (float*)d_out;

    dim3 grid(4, 8, 16);    // wot, row-group (7 tiles of 4 rows), batch
    dim3 block(512);
    conv3x3_mfma<<<grid, block, 0, stream>>>(x, w, bias, out);
}

// Round 6
// 57.912 us; speedup vs baseline: 8.8971x; 1.1956x over previous
//
#include <hip/hip_runtime.h>

// Conv2D 3x3 VALID NHWC, B=16 H=W=224 C=32 F=32 -> [16,222,222,32] fp32.
// im2col GEMM M=788544 K=288 N=32, bf16 MFMA 16x16x32 (swapped: D[filt][pix]).
// Round 6: R5 fixed stores (WRITE 98.5 MB ideal) but was VALU-limited by the
// manual RNE bf16 conversion done on every LDS read (~64 VALU per lane-tap;
// VALUBusy 31% = exactly the modeled cvt cost).
//  (1) v_perm_b32 truncation-pack: 2 f32 -> 2 bf16 per instruction (16x fewer
//      cvt ops). Weights stay RNE. absmax headroom 4.8x covers truncation.
//  (2) 3-buffer depth-2 prefetch (152 KB LDS): STAGE(t+2) in flight while
//      computing t, counted vmcnt(12) -- HBM queue never drains.

#define HO 222
#define WO 222
#define HIN 224
#define WIN 224
#define CIN 32
#define FOUT 32

#define TH 4                      // output rows per tile
#define TW 64                     // output cols per tile
#define IR (TH + 2)               // 6 staged rows
#define IC (TW + 2)               // 66 staged cols
#define NT 7                      // tiles per block
#define PIXB 128                  // bytes per staged fp32 pixel (32 ch)
#define STAGE_GR (IR * IC * 8)    // 3168 16B-granules per tile
#define BUF_GR (STAGE_GR + 64)    // slack for tail-wave fixed lane pattern
#define NSTG 7                    // ceil(3168/512) gload_lds per thread

typedef __attribute__((ext_vector_type(8))) short short8;
typedef __attribute__((ext_vector_type(4))) float float4v;

__device__ inline short f2bf(float f) {                  // RNE fp32->bf16 (weights only)
    unsigned u = __builtin_bit_cast(unsigned, f);
    unsigned r = (u + 0x7FFFu + ((u >> 16) & 1u)) >> 16;
    return (short)r;
}

__global__ __launch_bounds__(512, 2) void conv3x3_mfma(
    const float* __restrict__ x,     // [16,224,224,32]
    const float* __restrict__ w,     // [32][288 = (kh,kw,c)]
    const float* __restrict__ bias,  // [32]
    float* __restrict__ out)         // [16,222,222,32]
{
    __shared__ uint4 lds_raw[3][BUF_GR];   // 3 x 51712 B = 155136 B (1 block/CU)

    const int wot = blockIdx.x;            // 0..3
    const int g   = blockIdx.y;            // 0..7
    const int b   = blockIdx.z;            // 0..15
    const int wo_base = wot * TW;

    const int tid  = threadIdx.x;
    const int lane = tid & 63;
    const int wave = tid >> 6;             // 0..7

    const int fcol = lane & 15;            // A row (filter) / D col (pixel)
    const int kq   = lane >> 4;            // k-slice: k = kq*8 + i

    // ---- weights -> register A-fragments (lane: filter fcol, k-slice kq) ----
    short8 bfr[2][9];
#pragma unroll
    for (int h = 0; h < 2; ++h) {
        const float* wf = w + (h * 16 + fcol) * 288 + kq * 8;
#pragma unroll
        for (int s = 0; s < 9; ++s) {
            float4 lo = reinterpret_cast<const float4*>(wf + s * 32)[0];
            float4 hi = reinterpret_cast<const float4*>(wf + s * 32)[1];
            short8 v;
            v[0] = f2bf(lo.x); v[1] = f2bf(lo.y); v[2] = f2bf(lo.z); v[3] = f2bf(lo.w);
            v[4] = f2bf(hi.x); v[5] = f2bf(hi.y); v[6] = f2bf(hi.z); v[7] = f2bf(hi.w);
            bfr[h][s] = v;
        }
    }
    const float4 bias0 = reinterpret_cast<const float4*>(bias)[kq];      // filters kq*4..+3
    const float4 bias1 = reinterpret_cast<const float4*>(bias)[4 + kq];  // filters 16+kq*4..+3

    // ---- async staging: global fp32 -> LDS, source pre-swizzled (G21) ----
    auto STAGE = [&](int bufidx, int t) {
        char* buf = reinterpret_cast<char*>(lds_raw[bufidx]);
        const int row0 = (g * NT + t) * TH;
#pragma unroll
        for (int i = 0; i < NSTG; ++i) {
            if (i * 512 + (tid & ~63) < STAGE_GR) {            // whole-wave predicate
                int gid = tid + i * 512;                        // linear LDS granule
                int gg  = gid < STAGE_GR ? gid : STAGE_GR - 1;  // tail -> safe src, dest in slack
                int plin = gg >> 3;
                int sub  = (gg & 7) ^ (plin & 7);               // swizzled source granule
                int row  = plin / IC;
                int col  = plin - row * IC;
                int ir  = row0 + row;    if (ir  > HIN - 1) ir  = HIN - 1;
                int icl = wo_base + col; if (icl > WIN - 1) icl = WIN - 1;
                const float* src = x + ((b * HIN + ir) * WIN + icl) * CIN + sub * 4;
                __builtin_amdgcn_global_load_lds(
                    (const __attribute__((address_space(1))) void*)src,
                    (__attribute__((address_space(3))) void*)(buf + gid * 16),
                    16, 0, 0);
            }
        }
    };

    // ---------- prologue: 2 tiles in flight ----------
    STAGE(0, 0);
    STAGE(1, 1);

    // ---------- pipelined tile loop (depth-2 prefetch, counted vmcnt) ----------
#pragma unroll 1
    for (int t = 0; t < NT; ++t) {
        if (t + 2 < NT) {
            STAGE((t + 2) % 3, t + 2);
            // tile-t done when only t+1 (<=7) + t+2 (<=7) remain; per-wave
            // counts are 6 or 7 -> 12 is exact for 6+6 waves, mildly
            // conservative for the two 7-load waves.
            asm volatile("s_waitcnt vmcnt(12)" ::: "memory");
        } else if (t + 1 < NT) {
            asm volatile("s_waitcnt vmcnt(6)" ::: "memory");
        } else {
            asm volatile("s_waitcnt vmcnt(0)" ::: "memory");
        }
        __builtin_amdgcn_s_barrier();
        __builtin_amdgcn_sched_barrier(0);

        const char* buf = reinterpret_cast<const char*>(lds_raw[t % 3]);
        const int row0 = (g * NT + t) * TH;

#pragma unroll
        for (int j = 0; j < 2; ++j) {
            const int chunk = wave * 2 + j;                  // 16 chunks of 16 pixels
            const int pix = chunk * 16 + fcol;
            const int hoo = pix >> 6;
            const int woo = pix & 63;

            float4v acc0 = {0.f, 0.f, 0.f, 0.f};
            float4v acc1 = {0.f, 0.f, 0.f, 0.f};
#pragma unroll
            for (int s = 0; s < 9; ++s) {
                const int kh = s / 3, kw = s % 3;
                const int plin = (hoo + kh) * IC + (woo + kw);
                const int key = (plin & 7) << 4;
                const uint4 ua = *reinterpret_cast<const uint4*>(
                    buf + plin * PIXB + ((kq * 32) ^ key));       // ch kq*8..+3
                const uint4 ub = *reinterpret_cast<const uint4*>(
                    buf + plin * PIXB + ((kq * 32 + 16) ^ key));  // ch kq*8+4..+7
                // truncate-pack: bf16[i] = hi16(f32[i]); one v_perm per pair
                unsigned w0 = __builtin_amdgcn_perm(ua.y, ua.x, 0x07060302u);
                unsigned w1 = __builtin_amdgcn_perm(ua.w, ua.z, 0x07060302u);
                unsigned w2 = __builtin_amdgcn_perm(ub.y, ub.x, 0x07060302u);
                unsigned w3 = __builtin_amdgcn_perm(ub.w, ub.z, 0x07060302u);
                uint4 packed = {w0, w1, w2, w3};
                short8 a = __builtin_bit_cast(short8, packed);
                acc0 = __builtin_amdgcn_mfma_f32_16x16x32_bf16(bfr[0][s], a, acc0, 0, 0, 0);
                acc1 = __builtin_amdgcn_mfma_f32_16x16x32_bf16(bfr[1][s], a, acc1, 0, 0, 0);
            }

            // D[filter][pixel]: col(lane&15)=pixel, row=kq*4+r=filter
            const int ho = row0 + hoo;
            const int wo = wo_base + woo;
            if (ho < HO && wo < WO) {
                float* o = out + ((b * HO + ho) * WO + wo) * FOUT;
                float4 v0 = {acc0[0] + bias0.x, acc0[1] + bias0.y,
                             acc0[2] + bias0.z, acc0[3] + bias0.w};
                float4 v1 = {acc1[0] + bias1.x, acc1[1] + bias1.y,
                             acc1[2] + bias1.z, acc1[3] + bias1.w};
                reinterpret_cast<float4*>(o)[kq]     = v0;
                reinterpret_cast<float4*>(o)[4 + kq] = v1;
            }
        }

        __builtin_amdgcn_sched_barrier(0);
        __builtin_amdgcn_s_barrier();   // protect buf[t%3] before STAGE(t+3) reuses it
        __builtin_amdgcn_sched_barrier(0);
    }
}

extern "C" void kernel_launch(void* const* d_in, const int* in_sizes, int n_in,
                              void* d_out, int out_size, void* d_ws, size_t ws_size,
                              hipStream_t stream) {
    const float* x    = (const float*)d_in[0];
    const float* w    = (const float*)d_in[1];
    const float* bias = (const float*)d_in[2];
    float* out        = (float*)d_out;

    dim3 grid(4, 8, 16);    // wot, row-group (7 tiles of 4 rows), batch
    dim3 block(512);
    conv3x3_mfma<<<grid, block, 0, stream>>>(x, w, bias, out);
}